// Round 1
// baseline (283.317 us; speedup 1.0000x reference)
//
#include <hip/hip_runtime.h>
#include <stdint.h>

// SimplifiedLinearAttention: B=8, N=3136 (56x56), C=512, 8 heads x 64
// Pipeline: cvt -> transpose weights -> GEMM(QKV,fused act) -> kvmat/ksum ->
//           conv_dw -> attn(z,out,+fmap) -> GEMM(proj,+bias) -> f32 out
#define B_    8
#define N_    3136
#define C_    512
#define MTOT  25088   // B_*N_

typedef __attribute__((ext_vector_type(8))) short bf16x8;
typedef __attribute__((ext_vector_type(4))) float f32x4;

__device__ __forceinline__ float bf2f(short s){
  union { float f; uint32_t u; } cv; cv.u = ((uint32_t)(uint16_t)s) << 16; return cv.f;
}
__device__ __forceinline__ short f2bf(float f){
  union { float f; uint32_t u; } cv; cv.f = f;
  uint32_t r = cv.u + 0x7FFFu + ((cv.u >> 16) & 1u);
  return (short)(r >> 16);
}

typedef const __attribute__((address_space(1))) void* gas1_t;
typedef __attribute__((address_space(3))) void* las3_t;
__device__ __forceinline__ void gld16(const void* g, void* l){
  __builtin_amdgcn_global_load_lds((gas1_t)g, (las3_t)l, 16, 0, 0);
}

// ---------------- convert x to bf16 (vectorized) ----------------
__global__ __launch_bounds__(256) void cvt_x(const float* __restrict__ x,
                                             short* __restrict__ xb, int n8){
  int i = blockIdx.x * 256 + threadIdx.x;
  if (i >= n8) return;
  const float4* p = (const float4*)x;
  float4 a = p[i*2], b = p[i*2+1];
  short o[8] = { f2bf(a.x), f2bf(a.y), f2bf(a.z), f2bf(a.w),
                 f2bf(b.x), f2bf(b.y), f2bf(b.z), f2bf(b.w) };
  *(bf16x8*)(xb + i*8) = *(bf16x8*)o;
}

// -------- transpose+convert weights: dst[j*512 + k] = bf16(src[k*J + j]) ----
__global__ __launch_bounds__(256) void tconv(const float* __restrict__ src,
                                             short* __restrict__ dst, int J){
  __shared__ float tile[32][33];
  int jb = blockIdx.x * 32, kb = blockIdx.y * 32;
  int tx = threadIdx.x & 31, ty = threadIdx.x >> 5;   // ty 0..7
#pragma unroll
  for (int r = 0; r < 32; r += 8)
    tile[ty + r][tx] = src[(size_t)(kb + ty + r) * J + jb + tx];
  __syncthreads();
#pragma unroll
  for (int r = 0; r < 32; r += 8)
    dst[(size_t)(jb + ty + r) * 512 + kb + tx] = f2bf(tile[tx][ty + r]);
}

// ---------------- 128x128 bf16 MFMA GEMM, K=512, Bt is (N x K) ----------------
// MODE 0: QKV epilogue (relu q / relu(k+pos) / v, bf16 out)
// MODE 1: proj epilogue (+bias, f32 out)
template<int MODE>
__global__ __launch_bounds__(256)
void gemm_bf16(const short* __restrict__ A, const short* __restrict__ Bt,
               short* __restrict__ oQ, short* __restrict__ oK, short* __restrict__ oV,
               const float* __restrict__ posenc,
               float* __restrict__ oF, const float* __restrict__ bias)
{
  __shared__ __align__(16) short lA[128 * 32];   // [row][k] 64B rows
  __shared__ __align__(16) short lB[128 * 32];   // [n][k]
  const int t = threadIdx.x;
  const int wave = t >> 6, lane = t & 63;
  const int rt = blockIdx.y * 128;
  const int ct = blockIdx.x * 128;
  const int wm = (wave >> 1) * 64, wn = (wave & 1) * 64;
  const int fr = lane & 15;
  const int ko = (lane >> 4) << 3;   // 8 consecutive k per lane group

  f32x4 zv = {0.f, 0.f, 0.f, 0.f};
  f32x4 acc[4][4];
#pragma unroll
  for (int i = 0; i < 4; i++)
#pragma unroll
    for (int j = 0; j < 4; j++) acc[i][j] = zv;

  for (int kt = 0; kt < 16; ++kt) {
    const int k0 = kt << 5;
#pragma unroll
    for (int pass = 0; pass < 2; ++pass) {
      int wb = (wave << 6) + (pass << 8);   // wave-uniform chunk base
      int c  = wb + lane;
      int r  = c >> 2, kb = (c & 3) << 3;
      gld16(A  + (size_t)(rt + r) * 512 + k0 + kb, lA + wb * 8);
      gld16(Bt + (size_t)(ct + r) * 512 + k0 + kb, lB + wb * 8);
    }
    __syncthreads();   // drains vmcnt -> LDS tiles valid
    bf16x8 af[4], bfv[4];
#pragma unroll
    for (int i = 0; i < 4; i++) {
      af[i]  = *(const bf16x8*)&lA[(wm + i * 16 + fr) * 32 + ko];
      bfv[i] = *(const bf16x8*)&lB[(wn + i * 16 + fr) * 32 + ko];
    }
#pragma unroll
    for (int i = 0; i < 4; i++)
#pragma unroll
      for (int j = 0; j < 4; j++)
        acc[i][j] = __builtin_amdgcn_mfma_f32_16x16x32_bf16(af[i], bfv[j], acc[i][j], 0, 0, 0);
    __syncthreads();   // protect LDS before next stage
  }

  const int rb = (lane >> 4) << 2;   // D layout: row=(lane>>4)*4+reg, col=lane&15
#pragma unroll
  for (int i = 0; i < 4; i++) {
#pragma unroll
    for (int j = 0; j < 4; j++) {
#pragma unroll
      for (int r = 0; r < 4; r++) {
        int grow = rt + wm + i * 16 + rb + r;
        int gcol = ct + wn + j * 16 + fr;
        float v = acc[i][j][r];
        if (MODE == 0) {
          if (gcol < 512) {
            oQ[grow * 512 + gcol] = f2bf(fmaxf(v, 0.f));
          } else if (gcol < 1024) {
            int cc = gcol - 512;
            int n  = grow % N_;
            oK[grow * 512 + cc] = f2bf(fmaxf(v + posenc[n * 512 + cc], 0.f));
          } else {
            oV[grow * 512 + (gcol - 1024)] = f2bf(v);
          }
        } else {
          oF[(size_t)grow * 512 + gcol] = v + bias[gcol];
        }
      }
    }
  }
}

// ------------- per-head KtV (64x64) + ksum, f32 partials, N split 7 ----------
__global__ __launch_bounds__(256)
void kvmat_part(const short* __restrict__ kb, const short* __restrict__ vb,
                float* __restrict__ pKV, float* __restrict__ pKS)
{
  __shared__ __align__(16) float lk[64][64];
  __shared__ __align__(16) float lv[64][64];
  const int chunk = blockIdx.x, bh = blockIdx.y;
  const int b = bh >> 3, h = bh & 7;
  const int t = threadIdx.x;
  const int tc = t >> 4, td = t & 15;
  const int kc = t & 63, kr = (t >> 6) * 16;
  float acc[4][4] = {};
  float ksacc = 0.f;

  for (int tile = 0; tile < 7; ++tile) {
    const int r0 = chunk * 448 + tile * 64;
    __syncthreads();
#pragma unroll
    for (int i = 0; i < 2; i++) {
      int idx = t + i * 256;
      int r = idx >> 3, c8 = (idx & 7) << 3;
      size_t g = (size_t)(b * N_ + r0 + r) * 512 + h * 64 + c8;
      bf16x8 kk = *(const bf16x8*)(kb + g);
      bf16x8 vv = *(const bf16x8*)(vb + g);
#pragma unroll
      for (int e = 0; e < 8; e++) { lk[r][c8 + e] = bf2f(kk[e]); lv[r][c8 + e] = bf2f(vv[e]); }
    }
    __syncthreads();
#pragma unroll 4
    for (int r = 0; r < 64; r++) {
      f32x4 k4 = *(const f32x4*)&lk[r][tc * 4];
      f32x4 v4 = *(const f32x4*)&lv[r][td * 4];
#pragma unroll
      for (int i = 0; i < 4; i++)
#pragma unroll
        for (int j = 0; j < 4; j++) acc[i][j] += k4[i] * v4[j];
    }
#pragma unroll 4
    for (int rr = 0; rr < 16; rr++) ksacc += lk[kr + rr][kc];
  }

  const int pbase = (bh * 7 + chunk) * 4096;
#pragma unroll
  for (int i = 0; i < 4; i++)
#pragma unroll
    for (int j = 0; j < 4; j++)
      pKV[pbase + (tc * 4 + i) * 64 + td * 4 + j] = acc[i][j];
  __syncthreads();
  float* red = &lk[0][0];
  red[t] = ksacc;
  __syncthreads();
  if (t < 64)
    pKS[(bh * 7 + chunk) * 64 + t] = red[t] + red[t + 64] + red[t + 128] + red[t + 192];
}

__global__ __launch_bounds__(256)
void kv_reduce(const float* __restrict__ pKV, const float* __restrict__ pKS,
               float* __restrict__ kvm, float* __restrict__ ksum)
{
  int bh = blockIdx.x, t = threadIdx.x;
#pragma unroll
  for (int i = 0; i < 16; i++) {
    int idx = t + i * 256;
    float s = 0.f;
#pragma unroll
    for (int c = 0; c < 7; c++) s += pKV[(bh * 7 + c) * 4096 + idx];
    kvm[bh * 4096 + idx] = s;
  }
  if (t < 64) {
    float s = 0.f;
#pragma unroll
    for (int c = 0; c < 7; c++) s += pKS[(bh * 7 + c) * 64 + t];
    ksum[bh * 64 + t] = s;
  }
}

// ------------- depthwise 5x5 conv on v, +bias -> pre (bf16) -------------
__global__ __launch_bounds__(256)
void conv_dw(const short* __restrict__ vb, const float* __restrict__ w,
             const float* __restrict__ bias, short* __restrict__ pre)
{
  __shared__ __align__(16) short lsv[5 * 56 * 64];
  __shared__ float lw[1600];
  __shared__ float lb[64];
  const int y = blockIdx.x, bh = blockIdx.y;
  const int b = bh >> 3, h = bh & 7;
  const int t = threadIdx.x;
  for (int i = t; i < 1600; i += 256) lw[i] = w[i];
  if (t < 64) lb[t] = bias[t];
  for (int i = t; i < 2240; i += 256) {
    int row = i / 448, rem = i - row * 448;
    int xx = rem >> 3, c8 = (rem & 7) << 3;
    int gy = y + row - 2;
    bf16x8 val = {0, 0, 0, 0, 0, 0, 0, 0};
    if ((unsigned)gy < 56u)
      val = *(const bf16x8*)(vb + (size_t)(b * N_ + gy * 56 + xx) * 512 + h * 64 + c8);
    int byt = ((row * 56 + xx) * 64 + c8) * 2;
    byt ^= (xx & 7) << 4;                 // bank-conflict swizzle
    *(bf16x8*)((char*)lsv + byt) = val;
  }
  __syncthreads();
  const int x = t >> 2, dq = t & 3;
  if (x >= 56) return;
  float acc[16];
#pragma unroll
  for (int i = 0; i < 16; i++) acc[i] = lb[dq * 16 + i];
#pragma unroll
  for (int dy = 0; dy < 5; ++dy) {
#pragma unroll
    for (int dx = 0; dx < 5; ++dx) {
      int xx = x + dx - 2;
      if ((unsigned)xx < 56u) {
        int byt = ((dy * 56 + xx) * 64 + dq * 16) * 2;
        byt ^= (xx & 7) << 4;
        bf16x8 v0 = *(const bf16x8*)((const char*)lsv + byt);
        bf16x8 v1 = *(const bf16x8*)((const char*)lsv + (byt ^ 16));
#pragma unroll
        for (int e = 0; e < 8; e++) {
          acc[e]     += bf2f(v0[e]) * lw[(dq * 16 + e) * 25 + dy * 5 + dx];
          acc[e + 8] += bf2f(v1[e]) * lw[(dq * 16 + e + 8) * 25 + dy * 5 + dx];
        }
      }
    }
  }
  size_t base = (size_t)(b * N_ + y * 56 + x) * 512 + h * 64 + dq * 16;
  short o[16];
#pragma unroll
  for (int i = 0; i < 16; i++) o[i] = f2bf(acc[i]);
  *(bf16x8*)(pre + base)     = *(bf16x8*)&o[0];
  *(bf16x8*)(pre + base + 8) = *(bf16x8*)&o[8];
}

// ------- attn: out = (q . kvmat) * z + fmap, in-place on pre (bf16) -------
__global__ __launch_bounds__(256)
void attn_comb(const short* __restrict__ qb, const float* __restrict__ kvm,
               const float* __restrict__ ksum, short* __restrict__ pre)
{
  __shared__ __align__(16) float lkv[4096];
  __shared__ __align__(16) float lq[4096];   // [c][p] transposed
  __shared__ float lks[64];
  const int pt = blockIdx.x, bh = blockIdx.y;
  const int b = bh >> 3, h = bh & 7;
  const int t = threadIdx.x;
  for (int i = t; i < 4096; i += 256) lkv[i] = kvm[bh * 4096 + i];
  if (t < 64) lks[t] = ksum[bh * 64 + t];
  {
    const int p = t & 63, cg = t >> 6;
    size_t g = (size_t)(b * N_ + pt * 64 + p) * 512 + h * 64 + cg * 16;
    bf16x8 qa = *(const bf16x8*)(qb + g);
    bf16x8 qc = *(const bf16x8*)(qb + g + 8);
#pragma unroll
    for (int e = 0; e < 8; e++) {
      lq[(cg * 16 + e) * 64 + p]     = bf2f(qa[e]);
      lq[(cg * 16 + 8 + e) * 64 + p] = bf2f(qc[e]);
    }
  }
  __syncthreads();
  const int p = t & 63, d0 = (t >> 6) * 16;
  float acc[16] = {};
  float zd = 0.f;
#pragma unroll 4
  for (int c = 0; c < 64; c++) {
    float qv = lq[c * 64 + p];
    zd += qv * lks[c];
    const f32x4* row = (const f32x4*)&lkv[c * 64 + d0];
    f32x4 m0 = row[0], m1 = row[1], m2 = row[2], m3 = row[3];
#pragma unroll
    for (int e = 0; e < 4; e++) {
      acc[e]      += qv * m0[e];
      acc[4 + e]  += qv * m1[e];
      acc[8 + e]  += qv * m2[e];
      acc[12 + e] += qv * m3[e];
    }
  }
  float z = 1.f / (zd + 1e-6f);
  size_t base = (size_t)(b * N_ + pt * 64 + p) * 512 + h * 64 + d0;
  bf16x8 f0 = *(const bf16x8*)(pre + base);
  bf16x8 f1 = *(const bf16x8*)(pre + base + 8);
  short o[16];
#pragma unroll
  for (int e = 0; e < 8; e++) {
    o[e]     = f2bf(acc[e] * z + bf2f(f0[e]));
    o[e + 8] = f2bf(acc[e + 8] * z + bf2f(f1[e]));
  }
  *(bf16x8*)(pre + base)     = *(bf16x8*)&o[0];
  *(bf16x8*)(pre + base + 8) = *(bf16x8*)&o[8];
}

// ---------------------------------------------------------------------------
extern "C" void kernel_launch(void* const* d_in, const int* in_sizes, int n_in,
                              void* d_out, int out_size, void* d_ws, size_t ws_size,
                              hipStream_t stream)
{
  const float* x     = (const float*)d_in[0];
  const float* Wq    = (const float*)d_in[3];
  const float* Wkv   = (const float*)d_in[4];
  const float* pos   = (const float*)d_in[5];
  const float* dwcw  = (const float*)d_in[6];
  const float* dwcb  = (const float*)d_in[7];
  const float* Wproj = (const float*)d_in[8];
  const float* bproj = (const float*)d_in[9];
  float* out = (float*)d_out;

  char* ws = (char*)d_ws;
  size_t off = 0;
  auto alloc = [&](size_t bytes) -> void* {
    void* p = ws + off;
    off = (off + bytes + 255) & ~(size_t)255;
    return p;
  };
  short* xb     = (short*)alloc((size_t)MTOT * 512 * 2);
  short* wqkvT  = (short*)alloc((size_t)1536 * 512 * 2);
  short* wprojT = (short*)alloc((size_t)512 * 512 * 2);
  short* qb     = (short*)alloc((size_t)MTOT * 512 * 2);
  short* kbuf   = (short*)alloc((size_t)MTOT * 512 * 2);
  short* vbuf   = (short*)alloc((size_t)MTOT * 512 * 2);
  float* pKV    = (float*)alloc((size_t)64 * 7 * 4096 * 4);
  float* pKS    = (float*)alloc((size_t)64 * 7 * 64 * 4);
  float* kvm    = (float*)alloc((size_t)64 * 4096 * 4);
  float* ksumB  = (float*)alloc((size_t)64 * 64 * 4);
  short* pre    = (short*)alloc((size_t)MTOT * 512 * 2);
  if (ws_size < off) return;   // workspace too small: leave output zeroed (visible failure)

  // 1. convert x
  cvt_x<<<dim3((MTOT * 512 / 8 + 255) / 256), dim3(256), 0, stream>>>(x, xb, MTOT * 512 / 8);
  // 2. transpose weights -> (N x K) bf16
  tconv<<<dim3(16, 16), dim3(256), 0, stream>>>(Wq,    wqkvT,              512);
  tconv<<<dim3(32, 16), dim3(256), 0, stream>>>(Wkv,   wqkvT + 512 * 512, 1024);
  tconv<<<dim3(16, 16), dim3(256), 0, stream>>>(Wproj, wprojT,             512);
  // 3. QKV GEMM, fused activations
  gemm_bf16<0><<<dim3(12, 196), dim3(256), 0, stream>>>(xb, wqkvT, qb, kbuf, vbuf, pos,
                                                        nullptr, nullptr);
  // 4. per-head KtV + ksum
  kvmat_part<<<dim3(7, 64), dim3(256), 0, stream>>>(kbuf, vbuf, pKV, pKS);
  kv_reduce<<<dim3(64), dim3(256), 0, stream>>>(pKV, pKS, kvm, ksumB);
  // 5. depthwise conv -> pre
  conv_dw<<<dim3(56, 64), dim3(256), 0, stream>>>(vbuf, dwcw, dwcb, pre);
  // 6. attention output + fmap (in-place on pre)
  attn_comb<<<dim3(49, 64), dim3(256), 0, stream>>>(qb, kvm, ksumB, pre);
  // 7. projection GEMM -> f32 out
  gemm_bf16<1><<<dim3(4, 196), dim3(256), 0, stream>>>(pre, wprojT, nullptr, nullptr, nullptr,
                                                       nullptr, out, bproj);
}

// Round 3
// 268.790 us; speedup vs baseline: 1.0540x; 1.0540x over previous
//
#include <hip/hip_runtime.h>
#include <stdint.h>

// SimplifiedLinearAttention: B=8, N=3136 (56x56), C=512, 8 heads x 64
// Pipeline: cvt -> transpose weights -> GEMM(QKV,fused act) -> kvmat/ksum ->
//           conv_dw -> attn(z,out,+fmap) -> GEMM(proj,+bias) -> f32 out
// R3: GEMM = 2-slot double-buffer, ONE __syncthreads per K-tile (safe fence:
//     stage next tile issued before compute, barrier drain covers it).
//     Keeps both-sides LDS XOR swizzle + vectorized LDS-restaged epilogue
//     (<=36.9 KB LDS). Adds bijective XCD-aware block swizzle.
#define B_    8
#define N_    3136
#define C_    512
#define MTOT  25088   // B_*N_

typedef __attribute__((ext_vector_type(8))) short bf16x8;
typedef __attribute__((ext_vector_type(4))) float f32x4;

__device__ __forceinline__ float bf2f(short s){
  union { float f; uint32_t u; } cv; cv.u = ((uint32_t)(uint16_t)s) << 16; return cv.f;
}
__device__ __forceinline__ short f2bf(float f){
  union { float f; uint32_t u; } cv; cv.f = f;
  uint32_t r = cv.u + 0x7FFFu + ((cv.u >> 16) & 1u);
  return (short)(r >> 16);
}

typedef const __attribute__((address_space(1))) void* gas1_t;
typedef __attribute__((address_space(3))) void* las3_t;
__device__ __forceinline__ void gld16(const void* g, void* l){
  __builtin_amdgcn_global_load_lds((gas1_t)g, (las3_t)l, 16, 0, 0);
}

// ---------------- convert x to bf16 (vectorized) ----------------
__global__ __launch_bounds__(256) void cvt_x(const float* __restrict__ x,
                                             short* __restrict__ xb, int n8){
  int i = blockIdx.x * 256 + threadIdx.x;
  if (i >= n8) return;
  const float4* p = (const float4*)x;
  float4 a = p[i*2], b = p[i*2+1];
  short o[8] = { f2bf(a.x), f2bf(a.y), f2bf(a.z), f2bf(a.w),
                 f2bf(b.x), f2bf(b.y), f2bf(b.z), f2bf(b.w) };
  *(bf16x8*)(xb + i*8) = *(bf16x8*)o;
}

// -------- transpose+convert weights: dst[j*512 + k] = bf16(src[k*J + j]) ----
__global__ __launch_bounds__(256) void tconv(const float* __restrict__ src,
                                             short* __restrict__ dst, int J){
  __shared__ float tile[32][33];
  int jb = blockIdx.x * 32, kb = blockIdx.y * 32;
  int tx = threadIdx.x & 31, ty = threadIdx.x >> 5;   // ty 0..7
#pragma unroll
  for (int r = 0; r < 32; r += 8)
    tile[ty + r][tx] = src[(size_t)(kb + ty + r) * J + jb + tx];
  __syncthreads();
#pragma unroll
  for (int r = 0; r < 32; r += 8)
    dst[(size_t)(jb + ty + r) * 512 + kb + tx] = f2bf(tile[tx][ty + r]);
}

// ---------------- 128x128 bf16 MFMA GEMM, K=512, Bt is (N x K) ----------------
// 2-slot double buffer (16 KB each). Per K-tile: stage(kt+1) -> ds_read/MFMA
// tile kt -> __syncthreads (vmcnt0 drain = fence; also retires slot reads).
// Swizzle: 16B-chunk index phys = log ^ (row&3) ^ ((row>>2)&3) (involution),
// applied to the global SOURCE at stage time and to the ds_read address.
// MODE 0: QKV epilogue (relu q / relu(k+pos) / v, bf16 out, LDS-restaged)
// MODE 1: proj epilogue (+bias, f32 out, LDS-restaged in two row-halves)
template<int MODE, int GX>
__global__ __launch_bounds__(256)
void gemm_bf16(const short* __restrict__ A, const short* __restrict__ Bt,
               short* __restrict__ oQ, short* __restrict__ oK, short* __restrict__ oV,
               const float* __restrict__ posenc,
               float* __restrict__ oF, const float* __restrict__ bias)
{
  __shared__ __align__(16) char lds[MODE ? 33792 : 36864];
  constexpr int NT = 16;                            // K/32
  const int t = threadIdx.x;
  const int wave = t >> 6, lane = t & 63;

  // bijective XCD swizzle: grid count divisible by 8 in both uses
  const int nwg  = GX * 196;
  const int orig = blockIdx.y * GX + blockIdx.x;
  const int swz  = (orig & 7) * (nwg >> 3) + (orig >> 3);
  const int rt = (swz / GX) * 128;
  const int ct = (swz % GX) * 128;

  const int wm = (wave >> 1) * 64, wn = (wave & 1) * 64;
  const int fr = lane & 15;

  // ---- staging addressing (global source pre-swizzled; LDS dest linear) ----
  const int row0 = t >> 2;                                     // 0..63
  const int s0   = ((t & 3) ^ (row0 & 3) ^ ((row0 >> 2) & 3)) << 3;  // shorts
  const short* aBase = A  + (size_t)(rt + row0) * 512 + s0;
  const short* bBase = Bt + (size_t)(ct + row0) * 512 + s0;
  char* dBase = lds + wave * 1024;    // wave-uniform; HW adds lane*16

  auto stage = [&](int kt2) {
    char* d = dBase + (kt2 & 1) * 16384;
    const short* a0 = aBase + kt2 * 32;
    const short* b0 = bBase + kt2 * 32;
    gld16(a0,         d);            // A rows 0-63
    gld16(a0 + 32768, d + 4096);     // A rows 64-127  (+64*512 shorts)
    gld16(b0,         d + 8192);     // B rows 0-63
    gld16(b0 + 32768, d + 12288);    // B rows 64-127
  };

  // ---- fragment ds_read offsets (bytes, swizzled; row&3 / (row>>2)&3 are
  //      invariant under +16*m so one offset per operand suffices) ----
  const int rowA = wm + fr;
  const int offA = rowA * 64 + (((lane >> 4) ^ (rowA & 3) ^ ((rowA >> 2) & 3)) << 4);
  const int rowB = wn + fr;
  const int offB = 8192 + rowB * 64 + (((lane >> 4) ^ (rowB & 3) ^ ((rowB >> 2) & 3)) << 4);

  f32x4 zv = {0.f, 0.f, 0.f, 0.f};
  f32x4 acc[4][4];
#pragma unroll
  for (int i = 0; i < 4; i++)
#pragma unroll
    for (int j = 0; j < 4; j++) acc[i][j] = zv;

  stage(0);
  __syncthreads();                       // tile 0 landed (full drain)

  for (int kt = 0; kt < NT; ++kt) {
    if (kt + 1 < NT) stage(kt + 1);      // other slot; prev reads done at
                                         // the barrier that ended kt-1
    const char* slb = lds + (kt & 1) * 16384;
    bf16x8 af[4], bfv[4];
#pragma unroll
    for (int i = 0; i < 4; i++) {
      af[i]  = *(const bf16x8*)(slb + offA + i * 1024);
      bfv[i] = *(const bf16x8*)(slb + offB + i * 1024);
    }
#pragma unroll
    for (int i = 0; i < 4; i++)
#pragma unroll
      for (int j = 0; j < 4; j++)
        acc[i][j] = __builtin_amdgcn_mfma_f32_16x16x32_bf16(af[i], bfv[j], acc[i][j], 0, 0, 0);
    __syncthreads();                     // drains stage(kt+1); slot reads done
  }

  // ---- epilogue: restage C tile through LDS, vectorized coalesced stores ----
  const int rb = (lane >> 4) << 2;       // D layout: row=(lane>>4)*4+reg
  if (MODE == 0) {
    short* ov = (short*)lds;             // [128][144] bf16 (36864 B)
    const int sel = ct >> 9;             // 0:Q 1:K 2:V (uniform per block)
    const int cb  = ct - sel * 512;
#pragma unroll
    for (int i = 0; i < 4; i++)
#pragma unroll
      for (int j = 0; j < 4; j++)
#pragma unroll
        for (int r = 0; r < 4; r++) {
          int row = wm + i * 16 + rb + r;
          int col = wn + j * 16 + fr;
          float v = acc[i][j][r];
          if (sel == 0) v = fmaxf(v, 0.f);
          if (sel == 1) {
            int nr = (rt + row) % N_;
            v = fmaxf(v + posenc[nr * 512 + cb + col], 0.f);
          }
          ov[row * 144 + col] = f2bf(v);
        }
    __syncthreads();
    short* outp = sel == 0 ? oQ : (sel == 1 ? oK : oV);
#pragma unroll
    for (int pass = 0; pass < 8; ++pass) {
      int row  = (t >> 4) + pass * 16;
      int colb = (t & 15) * 8;
      bf16x8 vv = *(const bf16x8*)&ov[row * 144 + colb];
      *(bf16x8*)(outp + (size_t)(rt + row) * 512 + cb + colb) = vv;
    }
  } else {
    float* ovf = (float*)lds;            // [64][132] f32 (33792 B), 2 halves
#pragma unroll
    for (int half = 0; half < 2; ++half) {
      if (half) __syncthreads();         // protect prev half's reads
      if ((wave >> 1) == half) {         // waves owning rows half*64..+63
#pragma unroll
        for (int i = 0; i < 4; i++)
#pragma unroll
          for (int j = 0; j < 4; j++)
#pragma unroll
            for (int r = 0; r < 4; r++)
              ovf[(i * 16 + rb + r) * 132 + wn + j * 16 + fr] = acc[i][j][r];
      }
      __syncthreads();
#pragma unroll
      for (int pass = 0; pass < 4; ++pass) {
        int row  = (t >> 4) + pass * 16;   // 0..63
        int colb = (t & 15) * 8;
        f32x4 v0 = *(const f32x4*)&ovf[row * 132 + colb];
        f32x4 v1 = *(const f32x4*)&ovf[row * 132 + colb + 4];
        f32x4 b0 = *(const f32x4*)&bias[ct + colb];
        f32x4 b1 = *(const f32x4*)&bias[ct + colb + 4];
        v0 += b0; v1 += b1;
        float* op = oF + (size_t)(rt + half * 64 + row) * 512 + ct + colb;
        *(f32x4*)op       = v0;
        *(f32x4*)(op + 4) = v1;
      }
    }
  }
}

// ------------- per-head KtV (64x64) + ksum, f32 partials, N split 7 ----------
__global__ __launch_bounds__(256)
void kvmat_part(const short* __restrict__ kb, const short* __restrict__ vb,
                float* __restrict__ pKV, float* __restrict__ pKS)
{
  __shared__ __align__(16) float lk[64][64];
  __shared__ __align__(16) float lv[64][64];
  const int chunk = blockIdx.x, bh = blockIdx.y;
  const int b = bh >> 3, h = bh & 7;
  const int t = threadIdx.x;
  const int tc = t >> 4, td = t & 15;
  const int kc = t & 63, kr = (t >> 6) * 16;
  float acc[4][4] = {};
  float ksacc = 0.f;

  for (int tile = 0; tile < 7; ++tile) {
    const int r0 = chunk * 448 + tile * 64;
    __syncthreads();
#pragma unroll
    for (int i = 0; i < 2; i++) {
      int idx = t + i * 256;
      int r = idx >> 3, c8 = (idx & 7) << 3;
      size_t g = (size_t)(b * N_ + r0 + r) * 512 + h * 64 + c8;
      bf16x8 kk = *(const bf16x8*)(kb + g);
      bf16x8 vv = *(const bf16x8*)(vb + g);
#pragma unroll
      for (int e = 0; e < 8; e++) { lk[r][c8 + e] = bf2f(kk[e]); lv[r][c8 + e] = bf2f(vv[e]); }
    }
    __syncthreads();
#pragma unroll 4
    for (int r = 0; r < 64; r++) {
      f32x4 k4 = *(const f32x4*)&lk[r][tc * 4];
      f32x4 v4 = *(const f32x4*)&lv[r][td * 4];
#pragma unroll
      for (int i = 0; i < 4; i++)
#pragma unroll
        for (int j = 0; j < 4; j++) acc[i][j] += k4[i] * v4[j];
    }
#pragma unroll 4
    for (int rr = 0; rr < 16; rr++) ksacc += lk[kr + rr][kc];
  }

  const int pbase = (bh * 7 + chunk) * 4096;
#pragma unroll
  for (int i = 0; i < 4; i++)
#pragma unroll
    for (int j = 0; j < 4; j++)
      pKV[pbase + (tc * 4 + i) * 64 + td * 4 + j] = acc[i][j];
  __syncthreads();
  float* red = &lk[0][0];
  red[t] = ksacc;
  __syncthreads();
  if (t < 64)
    pKS[(bh * 7 + chunk) * 64 + t] = red[t] + red[t + 64] + red[t + 128] + red[t + 192];
}

__global__ __launch_bounds__(256)
void kv_reduce(const float* __restrict__ pKV, const float* __restrict__ pKS,
               float* __restrict__ kvm, float* __restrict__ ksum)
{
  int bh = blockIdx.x, t = threadIdx.x;
#pragma unroll
  for (int i = 0; i < 16; i++) {
    int idx = t + i * 256;
    float s = 0.f;
#pragma unroll
    for (int c = 0; c < 7; c++) s += pKV[(bh * 7 + c) * 4096 + idx];
    kvm[bh * 4096 + idx] = s;
  }
  if (t < 64) {
    float s = 0.f;
#pragma unroll
    for (int c = 0; c < 7; c++) s += pKS[(bh * 7 + c) * 64 + t];
    ksum[bh * 64 + t] = s;
  }
}

// ------------- depthwise 5x5 conv on v, +bias -> pre (bf16) -------------
__global__ __launch_bounds__(256)
void conv_dw(const short* __restrict__ vb, const float* __restrict__ w,
             const float* __restrict__ bias, short* __restrict__ pre)
{
  __shared__ __align__(16) short lsv[5 * 56 * 64];
  __shared__ float lw[1600];
  __shared__ float lb[64];
  const int y = blockIdx.x, bh = blockIdx.y;
  const int b = bh >> 3, h = bh & 7;
  const int t = threadIdx.x;
  for (int i = t; i < 1600; i += 256) lw[i] = w[i];
  if (t < 64) lb[t] = bias[t];
  for (int i = t; i < 2240; i += 256) {
    int row = i / 448, rem = i - row * 448;
    int xx = rem >> 3, c8 = (rem & 7) << 3;
    int gy = y + row - 2;
    bf16x8 val = {0, 0, 0, 0, 0, 0, 0, 0};
    if ((unsigned)gy < 56u)
      val = *(const bf16x8*)(vb + (size_t)(b * N_ + gy * 56 + xx) * 512 + h * 64 + c8);
    int byt = ((row * 56 + xx) * 64 + c8) * 2;
    byt ^= (xx & 7) << 4;                 // bank-conflict swizzle
    *(bf16x8*)((char*)lsv + byt) = val;
  }
  __syncthreads();
  const int x = t >> 2, dq = t & 3;
  if (x >= 56) return;
  float acc[16];
#pragma unroll
  for (int i = 0; i < 16; i++) acc[i] = lb[dq * 16 + i];
#pragma unroll
  for (int dy = 0; dy < 5; ++dy) {
#pragma unroll
    for (int dx = 0; dx < 5; ++dx) {
      int xx = x + dx - 2;
      if ((unsigned)xx < 56u) {
        int byt = ((dy * 56 + xx) * 64 + dq * 16) * 2;
        byt ^= (xx & 7) << 4;
        bf16x8 v0 = *(const bf16x8*)((const char*)lsv + byt);
        bf16x8 v1 = *(const bf16x8*)((const char*)lsv + (byt ^ 16));
#pragma unroll
        for (int e = 0; e < 8; e++) {
          acc[e]     += bf2f(v0[e]) * lw[(dq * 16 + e) * 25 + dy * 5 + dx];
          acc[e + 8] += bf2f(v1[e]) * lw[(dq * 16 + e + 8) * 25 + dy * 5 + dx];
        }
      }
    }
  }
  size_t base = (size_t)(b * N_ + y * 56 + x) * 512 + h * 64 + dq * 16;
  short o[16];
#pragma unroll
  for (int i = 0; i < 16; i++) o[i] = f2bf(acc[i]);
  *(bf16x8*)(pre + base)     = *(bf16x8*)&o[0];
  *(bf16x8*)(pre + base + 8) = *(bf16x8*)&o[8];
}

// ------- attn: out = (q . kvmat) * z + fmap, in-place on pre (bf16) -------
__global__ __launch_bounds__(256)
void attn_comb(const short* __restrict__ qb, const float* __restrict__ kvm,
               const float* __restrict__ ksum, short* __restrict__ pre)
{
  __shared__ __align__(16) float lkv[4096];
  __shared__ __align__(16) float lq[4096];   // [c][p] transposed
  __shared__ float lks[64];
  const int pt = blockIdx.x, bh = blockIdx.y;
  const int b = bh >> 3, h = bh & 7;
  const int t = threadIdx.x;
  for (int i = t; i < 4096; i += 256) lkv[i] = kvm[bh * 4096 + i];
  if (t < 64) lks[t] = ksum[bh * 64 + t];
  {
    const int p = t & 63, cg = t >> 6;
    size_t g = (size_t)(b * N_ + pt * 64 + p) * 512 + h * 64 + cg * 16;
    bf16x8 qa = *(const bf16x8*)(qb + g);
    bf16x8 qc = *(const bf16x8*)(qb + g + 8);
#pragma unroll
    for (int e = 0; e < 8; e++) {
      lq[(cg * 16 + e) * 64 + p]     = bf2f(qa[e]);
      lq[(cg * 16 + 8 + e) * 64 + p] = bf2f(qc[e]);
    }
  }
  __syncthreads();
  const int p = t & 63, d0 = (t >> 6) * 16;
  float acc[16] = {};
  float zd = 0.f;
#pragma unroll 4
  for (int c = 0; c < 64; c++) {
    float qv = lq[c * 64 + p];
    zd += qv * lks[c];
    const f32x4* row = (const f32x4*)&lkv[c * 64 + d0];
    f32x4 m0 = row[0], m1 = row[1], m2 = row[2], m3 = row[3];
#pragma unroll
    for (int e = 0; e < 4; e++) {
      acc[e]      += qv * m0[e];
      acc[4 + e]  += qv * m1[e];
      acc[8 + e]  += qv * m2[e];
      acc[12 + e] += qv * m3[e];
    }
  }
  float z = 1.f / (zd + 1e-6f);
  size_t base = (size_t)(b * N_ + pt * 64 + p) * 512 + h * 64 + d0;
  bf16x8 f0 = *(const bf16x8*)(pre + base);
  bf16x8 f1 = *(const bf16x8*)(pre + base + 8);
  short o[16];
#pragma unroll
  for (int e = 0; e < 8; e++) {
    o[e]     = f2bf(acc[e] * z + bf2f(f0[e]));
    o[e + 8] = f2bf(acc[e + 8] * z + bf2f(f1[e]));
  }
  *(bf16x8*)(pre + base)     = *(bf16x8*)&o[0];
  *(bf16x8*)(pre + base + 8) = *(bf16x8*)&o[8];
}

// ---------------------------------------------------------------------------
extern "C" void kernel_launch(void* const* d_in, const int* in_sizes, int n_in,
                              void* d_out, int out_size, void* d_ws, size_t ws_size,
                              hipStream_t stream)
{
  const float* x     = (const float*)d_in[0];
  const float* Wq    = (const float*)d_in[3];
  const float* Wkv   = (const float*)d_in[4];
  const float* pos   = (const float*)d_in[5];
  const float* dwcw  = (const float*)d_in[6];
  const float* dwcb  = (const float*)d_in[7];
  const float* Wproj = (const float*)d_in[8];
  const float* bproj = (const float*)d_in[9];
  float* out = (float*)d_out;

  char* ws = (char*)d_ws;
  size_t off = 0;
  auto alloc = [&](size_t bytes) -> void* {
    void* p = ws + off;
    off = (off + bytes + 255) & ~(size_t)255;
    return p;
  };
  short* xb     = (short*)alloc((size_t)MTOT * 512 * 2);
  short* wqkvT  = (short*)alloc((size_t)1536 * 512 * 2);
  short* wprojT = (short*)alloc((size_t)512 * 512 * 2);
  short* qb     = (short*)alloc((size_t)MTOT * 512 * 2);
  short* kbuf   = (short*)alloc((size_t)MTOT * 512 * 2);
  short* vbuf   = (short*)alloc((size_t)MTOT * 512 * 2);
  float* pKV    = (float*)alloc((size_t)64 * 7 * 4096 * 4);
  float* pKS    = (float*)alloc((size_t)64 * 7 * 64 * 4);
  float* kvm    = (float*)alloc((size_t)64 * 4096 * 4);
  float* ksumB  = (float*)alloc((size_t)64 * 64 * 4);
  short* pre    = (short*)alloc((size_t)MTOT * 512 * 2);
  if (ws_size < off) return;   // workspace too small: leave output zeroed (visible failure)

  // 1. convert x
  cvt_x<<<dim3((MTOT * 512 / 8 + 255) / 256), dim3(256), 0, stream>>>(x, xb, MTOT * 512 / 8);
  // 2. transpose weights -> (N x K) bf16
  tconv<<<dim3(16, 16), dim3(256), 0, stream>>>(Wq,    wqkvT,              512);
  tconv<<<dim3(32, 16), dim3(256), 0, stream>>>(Wkv,   wqkvT + 512 * 512, 1024);
  tconv<<<dim3(16, 16), dim3(256), 0, stream>>>(Wproj, wprojT,             512);
  // 3. QKV GEMM, fused activations
  gemm_bf16<0, 12><<<dim3(12, 196), dim3(256), 0, stream>>>(xb, wqkvT, qb, kbuf, vbuf, pos,
                                                            nullptr, nullptr);
  // 4. per-head KtV + ksum
  kvmat_part<<<dim3(7, 64), dim3(256), 0, stream>>>(kbuf, vbuf, pKV, pKS);
  kv_reduce<<<dim3(64), dim3(256), 0, stream>>>(pKV, pKS, kvm, ksumB);
  // 5. depthwise conv -> pre
  conv_dw<<<dim3(56, 64), dim3(256), 0, stream>>>(vbuf, dwcw, dwcb, pre);
  // 6. attention output + fmap (in-place on pre)
  attn_comb<<<dim3(49, 64), dim3(256), 0, stream>>>(qb, kvm, ksumB, pre);
  // 7. projection GEMM -> f32 out
  gemm_bf16<1, 4><<<dim3(4, 196), dim3(256), 0, stream>>>(pre, wprojT, nullptr, nullptr, nullptr,
                                                          nullptr, out, bproj);
}